// Round 1
// baseline (4766.077 us; speedup 1.0000x reference)
//
#include <hip/hip_runtime.h>
#include <hip/hip_bf16.h>
#include <math.h>

// ---------------------------------------------------------------------------
// Problem: B=32, N=128, D=5000, H=256, C=4
// Pipeline:
//   1) x_tilde[4096,256] = x[4096,5000] @ Er[256,5000]^T          (gemm_nt)
//   2) P[4096,1536]      = x_tilde @ {Wsr_r,Wsr_z,Wsr_h,Wr_r,Wr_z,Wr_h}^T
//   3) UT = transpose of 9 U matrices (for coalesced matvec in scan)
//   4) tree_scan: 32 WGs (1/tree) x 256 thr (1/hidden), 128 sequential steps
//   5) epilogue: leaf-masked max over nodes -> logits -> softmax
// ---------------------------------------------------------------------------

#define H_DIM 256
#define N_NODES 128
#define B_TREES 32

__device__ __forceinline__ float sigmoidf_(float x) {
    return 1.0f / (1.0f + expf(-x));
}

// C[M,N] = A[M,K] @ B[N,K]^T   (both row-major, K contiguous; M,N mult of 64)
// grid = (M/64, N/64), 256 threads. ldc = row stride of C.
__global__ __launch_bounds__(256) void gemm_nt(
    const float* __restrict__ A, const float* __restrict__ B,
    float* __restrict__ C, int K, int ldc) {
    __shared__ float As[64][68];
    __shared__ float Bs[64][68];
    const int tid = threadIdx.x;
    const int bm = blockIdx.x, bn = blockIdx.y;
    const int tx = tid & 15, ty = tid >> 4;
    float acc[4][4] = {{0.f}};
    const int nk = (K + 63) >> 6;
    for (int kt = 0; kt < nk; ++kt) {
        const int k0 = kt << 6;
#pragma unroll
        for (int it = 0; it < 4; ++it) {
            const int f = tid + it * 256;     // 0..1023 float4 slots
            const int row = f >> 4;           // 0..63
            const int cq = f & 15;            // 0..15 (float4 within row)
            const int kcol = k0 + cq * 4;
            float4 av = make_float4(0.f, 0.f, 0.f, 0.f);
            float4 bv = make_float4(0.f, 0.f, 0.f, 0.f);
            if (kcol < K) {  // K % 4 == 0 always here
                av = *(const float4*)(A + (size_t)(bm * 64 + row) * K + kcol);
                bv = *(const float4*)(B + (size_t)(bn * 64 + row) * K + kcol);
            }
            *(float4*)&As[row][cq * 4] = av;
            *(float4*)&Bs[row][cq * 4] = bv;
        }
        __syncthreads();
#pragma unroll 4
        for (int kk = 0; kk < 64; kk += 4) {
            float4 a[4], bq[4];
#pragma unroll
            for (int i = 0; i < 4; ++i) a[i] = *(const float4*)&As[ty * 4 + i][kk];
#pragma unroll
            for (int j = 0; j < 4; ++j) bq[j] = *(const float4*)&Bs[tx * 4 + j][kk];
#pragma unroll
            for (int i = 0; i < 4; ++i)
#pragma unroll
                for (int j = 0; j < 4; ++j)
                    acc[i][j] += a[i].x * bq[j].x + a[i].y * bq[j].y +
                                 a[i].z * bq[j].z + a[i].w * bq[j].w;
        }
        __syncthreads();
    }
#pragma unroll
    for (int i = 0; i < 4; ++i) {
        float4 o = make_float4(acc[i][0], acc[i][1], acc[i][2], acc[i][3]);
        *(float4*)(C + (size_t)(bm * 64 + ty * 4 + i) * ldc + bn * 64 + tx * 4) = o;
    }
}

// UT[m][j][h] = U_m[h][j]; grid (256, 9) x 256 threads
__global__ __launch_bounds__(256) void transpose_u(
    const float* __restrict__ U0, const float* __restrict__ U1,
    const float* __restrict__ U2, const float* __restrict__ U3,
    const float* __restrict__ U4, const float* __restrict__ U5,
    const float* __restrict__ U6, const float* __restrict__ U7,
    const float* __restrict__ U8, float* __restrict__ UT) {
    const float* Us[9] = {U0, U1, U2, U3, U4, U5, U6, U7, U8};
    const int j = blockIdx.x;
    const int m = blockIdx.y;
    const int h = threadIdx.x;
    UT[(size_t)m * 65536 + j * 256 + h] = Us[m][h * 256 + j];
}

// One workgroup per tree; thread h owns hidden unit h.
// UT order: 0 Usr_r, 1 Usr_z, 2 Usr_h, 3 Ur_r, 4 Ur_z, 5 Ur_h,
//           6 Usr2r_r, 7 Usr2r_z, 8 Usr2r_h
// P column blocks (w*256): 0 Wsr_r, 1 Wsr_z, 2 Wsr_h, 3 Wr_r, 4 Wr_z, 5 Wr_h
__global__ __launch_bounds__(256) void tree_scan(
    const float* __restrict__ P, const float* __restrict__ UT,
    const int* __restrict__ parents,
    float* __restrict__ Ssh, float* __restrict__ Sru) {
    const int b = blockIdx.x;
    const int h = threadIdx.x;
    __shared__ float hsp_s[H_DIM], hrp_s[H_DIM], v_s[H_DIM], hsh_s[H_DIM], v2_s[H_DIM];

    const float* U0 = UT + 0 * 65536;
    const float* U1 = UT + 1 * 65536;
    const float* U2 = UT + 2 * 65536;
    const float* U3 = UT + 3 * 65536;
    const float* U4 = UT + 4 * 65536;
    const float* U5 = UT + 5 * 65536;
    const float* U6 = UT + 6 * 65536;
    const float* U7 = UT + 7 * 65536;
    const float* U8 = UT + 8 * 65536;

    for (int i = 0; i < N_NODES; ++i) {
        const int p = parents[b * N_NODES + i];
        float hs = 0.f, hr = 0.f;
        if (p != 0) {
            hs = Ssh[((size_t)b * N_NODES + (p - 1)) * H_DIM + h];
            hr = Sru[((size_t)b * N_NODES + (p - 1)) * H_DIM + h];
        }
        hsp_s[h] = hs;
        hrp_s[h] = hr;
        __syncthreads();

        const float* Pi = P + ((size_t)b * N_NODES + i) * 1536;

        // stage 1: r_sh, z_sh
        float dr = 0.f, dz = 0.f;
#pragma unroll 8
        for (int j = 0; j < H_DIM; ++j) {
            const float hv = hsp_s[j];
            dr = fmaf(U0[j * 256 + h], hv, dr);
            dz = fmaf(U1[j * 256 + h], hv, dz);
        }
        const float r_sh = sigmoidf_(Pi[h] + dr);
        const float z_sh = sigmoidf_(Pi[256 + h] + dz);
        v_s[h] = hs * r_sh;
        __syncthreads();

        // stage 2: h_sh
        float dh = 0.f;
#pragma unroll 8
        for (int j = 0; j < H_DIM; ++j)
            dh = fmaf(U2[j * 256 + h], v_s[j], dh);
        const float hsh_t = tanhf(Pi[512 + h] + dh);
        const float h_sh = (1.f - z_sh) * hs + z_sh * hsh_t;
        hsh_s[h] = h_sh;
        Ssh[((size_t)b * N_NODES + i) * H_DIM + h] = h_sh;
        __syncthreads();

        // stage 3: r_ru, z_ru
        float er = 0.f, ez = 0.f, fr = 0.f, fz = 0.f;
#pragma unroll 4
        for (int j = 0; j < H_DIM; ++j) {
            const float hrv = hrp_s[j];
            const float hsv = hsh_s[j];
            er = fmaf(U3[j * 256 + h], hrv, er);
            ez = fmaf(U4[j * 256 + h], hrv, ez);
            fr = fmaf(U6[j * 256 + h], hsv, fr);
            fz = fmaf(U7[j * 256 + h], hsv, fz);
        }
        const float r_ru = sigmoidf_(Pi[768 + h] + er + fr);
        const float z_ru = sigmoidf_(Pi[1024 + h] + ez + fz);
        v2_s[h] = hr * r_ru;
        __syncthreads();

        // stage 4: h_ru
        float eh = 0.f, fh = 0.f;
#pragma unroll 8
        for (int j = 0; j < H_DIM; ++j) {
            eh = fmaf(U5[j * 256 + h], v2_s[j], eh);
            fh = fmaf(U8[j * 256 + h], hsh_s[j], fh);
        }
        const float hru_t = tanhf(Pi[1280 + h] + eh + fh);
        const float h_ru = (1.f - z_ru) * hr + z_ru * hru_t;
        Sru[((size_t)b * N_NODES + i) * H_DIM + h] = h_ru;
        __syncthreads();
    }
}

// One WG per tree: leaf-masked max over nodes, 4 logits, softmax.
__global__ __launch_bounds__(256) void epilogue_k(
    const float* __restrict__ Sru, const int* __restrict__ is_leaf,
    const float* __restrict__ Vr, const float* __restrict__ br,
    float* __restrict__ out) {
    const int b = blockIdx.x;
    const int h = threadIdx.x;
    float m = -3.402823466e38f;  // finfo(float32).min
    for (int n = 0; n < N_NODES; ++n) {
        const float v = Sru[((size_t)b * N_NODES + n) * H_DIM + h];
        if (is_leaf[b * N_NODES + n] != 0) m = fmaxf(m, v);
    }
    __shared__ float hm[H_DIM];
    __shared__ float lg[4];
    hm[h] = m;
    __syncthreads();
    if (h < 4) {
        float acc = br[h];
#pragma unroll 8
        for (int j = 0; j < H_DIM; ++j) acc = fmaf(Vr[h * 256 + j], hm[j], acc);
        lg[h] = acc;
    }
    __syncthreads();
    if (h == 0) {
        const float mx = fmaxf(fmaxf(lg[0], lg[1]), fmaxf(lg[2], lg[3]));
        const float e0 = expf(lg[0] - mx);
        const float e1 = expf(lg[1] - mx);
        const float e2 = expf(lg[2] - mx);
        const float e3 = expf(lg[3] - mx);
        const float s = e0 + e1 + e2 + e3;
        out[b * 4 + 0] = e0 / s;
        out[b * 4 + 1] = e1 / s;
        out[b * 4 + 2] = e2 / s;
        out[b * 4 + 3] = e3 / s;
    }
}

extern "C" void kernel_launch(void* const* d_in, const int* in_sizes, int n_in,
                              void* d_out, int out_size, void* d_ws, size_t ws_size,
                              hipStream_t stream) {
    const float* x      = (const float*)d_in[0];   // [32,128,5000]
    const float* Er     = (const float*)d_in[1];   // [256,5000]
    const float* Wsr_r  = (const float*)d_in[2];
    const float* Usr_r  = (const float*)d_in[3];
    const float* Wsr_z  = (const float*)d_in[4];
    const float* Usr_z  = (const float*)d_in[5];
    const float* Wsr_h  = (const float*)d_in[6];
    const float* Usr_h  = (const float*)d_in[7];
    const float* Wr_r   = (const float*)d_in[8];
    const float* Ur_r   = (const float*)d_in[9];
    const float* Usr2r_r= (const float*)d_in[10];
    const float* Wr_z   = (const float*)d_in[11];
    const float* Ur_z   = (const float*)d_in[12];
    const float* Usr2r_z= (const float*)d_in[13];
    const float* Wr_h   = (const float*)d_in[14];
    const float* Ur_h   = (const float*)d_in[15];
    const float* Usr2r_h= (const float*)d_in[16];
    const float* Vr     = (const float*)d_in[17];  // [4,256]
    const float* br     = (const float*)d_in[18];  // [4,1]
    const int*   parents= (const int*)d_in[19];    // [32,128]
    const int*   is_leaf= (const int*)d_in[20];    // [32,128]
    float* out = (float*)d_out;                    // [32,4]

    float* ws = (float*)d_ws;
    float* xt  = ws;                         // 4096*256      = 1,048,576
    float* P   = xt + 1048576;               // 4096*1536     = 6,291,456
    float* UT  = P + 6291456;                // 9*256*256     =   589,824
    float* Ssh = UT + 589824;                // 32*128*256    = 1,048,576
    float* Sru = Ssh + 1048576;              // 32*128*256    = 1,048,576

    dim3 blk(256);

    // 1) x_tilde = x @ Er^T   (M=4096, N=256, K=5000)
    gemm_nt<<<dim3(64, 4), blk, 0, stream>>>(x, Er, xt, 5000, 256);

    // 2) P = x_tilde @ {W}^T  (M=4096, N=256, K=256) x 6, column blocks of P
    const float* Ws[6] = {Wsr_r, Wsr_z, Wsr_h, Wr_r, Wr_z, Wr_h};
    for (int w = 0; w < 6; ++w)
        gemm_nt<<<dim3(64, 4), blk, 0, stream>>>(xt, Ws[w], P + w * 256, 256, 1536);

    // 3) transpose the 9 U matrices
    transpose_u<<<dim3(256, 9), blk, 0, stream>>>(
        Usr_r, Usr_z, Usr_h, Ur_r, Ur_z, Ur_h, Usr2r_r, Usr2r_z, Usr2r_h, UT);

    // 4) sequential tree-GRU scan, one WG per tree
    tree_scan<<<dim3(B_TREES), blk, 0, stream>>>(P, UT, parents, Ssh, Sru);

    // 5) epilogue
    epilogue_k<<<dim3(B_TREES), blk, 0, stream>>>(Sru, is_leaf, Vr, br, out);
}

// Round 2
// 2143.733 us; speedup vs baseline: 2.2233x; 2.2233x over previous
//
#include <hip/hip_runtime.h>
#include <hip/hip_bf16.h>
#include <hip/hip_cooperative_groups.h>
#include <math.h>

namespace cg = cooperative_groups;

// ---------------------------------------------------------------------------
// Problem: B=32, N=128, D=5000, H=256, C=4
// Pipeline:
//   1) x_tilde[4096,256] = x[4096,5000] @ Er[256,5000]^T          (gemm_nt)
//   2) P[4096,1536]      = x_tilde @ {Wsr_r,Wsr_z,Wsr_h,Wr_r,Wr_z,Wr_h}^T
//   3) UT = transpose of 9 U matrices (coalesced matvec in scan)
//   4) build_schedule: depth of each node (tree is random-recursive, expected
//      max depth ~e*ln(128) ~= 13..17) -> counting-sort nodes into levels
//   5) tree_scan_lp: cooperative kernel, grid.sync() between levels; nodes at
//      the same depth are independent -> ~300 node-updates in parallel/level.
//      Each WG batches 4 nodes so each U element load is reused 4x.
//   6) epilogue: leaf-masked max over nodes -> logits -> softmax
// ---------------------------------------------------------------------------

#define H_DIM 256
#define N_NODES 128
#define B_TREES 32
#define MAXL 128
#define TPB_NODES 4
#define GRID_WGS 256

__device__ __forceinline__ float sigmoidf_(float x) {
    return 1.0f / (1.0f + expf(-x));
}

// C[M,N] = A[M,K] @ B[N,K]^T   (row-major, K contiguous; M,N mult of 64)
__global__ __launch_bounds__(256) void gemm_nt(
    const float* __restrict__ A, const float* __restrict__ B,
    float* __restrict__ C, int K, int ldc) {
    __shared__ float As[64][68];
    __shared__ float Bs[64][68];
    const int tid = threadIdx.x;
    const int bm = blockIdx.x, bn = blockIdx.y;
    const int tx = tid & 15, ty = tid >> 4;
    float acc[4][4] = {{0.f}};
    const int nk = (K + 63) >> 6;
    for (int kt = 0; kt < nk; ++kt) {
        const int k0 = kt << 6;
#pragma unroll
        for (int it = 0; it < 4; ++it) {
            const int f = tid + it * 256;
            const int row = f >> 4;
            const int cq = f & 15;
            const int kcol = k0 + cq * 4;
            float4 av = make_float4(0.f, 0.f, 0.f, 0.f);
            float4 bv = make_float4(0.f, 0.f, 0.f, 0.f);
            if (kcol < K) {
                av = *(const float4*)(A + (size_t)(bm * 64 + row) * K + kcol);
                bv = *(const float4*)(B + (size_t)(bn * 64 + row) * K + kcol);
            }
            *(float4*)&As[row][cq * 4] = av;
            *(float4*)&Bs[row][cq * 4] = bv;
        }
        __syncthreads();
#pragma unroll 4
        for (int kk = 0; kk < 64; kk += 4) {
            float4 a[4], bq[4];
#pragma unroll
            for (int i = 0; i < 4; ++i) a[i] = *(const float4*)&As[ty * 4 + i][kk];
#pragma unroll
            for (int j = 0; j < 4; ++j) bq[j] = *(const float4*)&Bs[tx * 4 + j][kk];
#pragma unroll
            for (int i = 0; i < 4; ++i)
#pragma unroll
                for (int j = 0; j < 4; ++j)
                    acc[i][j] += a[i].x * bq[j].x + a[i].y * bq[j].y +
                                 a[i].z * bq[j].z + a[i].w * bq[j].w;
        }
        __syncthreads();
    }
#pragma unroll
    for (int i = 0; i < 4; ++i) {
        float4 o = make_float4(acc[i][0], acc[i][1], acc[i][2], acc[i][3]);
        *(float4*)(C + (size_t)(bm * 64 + ty * 4 + i) * ldc + bn * 64 + tx * 4) = o;
    }
}

// UT[m][j][h] = U_m[h][j]; grid (256, 9) x 256 threads
__global__ __launch_bounds__(256) void transpose_u(
    const float* __restrict__ U0, const float* __restrict__ U1,
    const float* __restrict__ U2, const float* __restrict__ U3,
    const float* __restrict__ U4, const float* __restrict__ U5,
    const float* __restrict__ U6, const float* __restrict__ U7,
    const float* __restrict__ U8, float* __restrict__ UT) {
    const float* Us[9] = {U0, U1, U2, U3, U4, U5, U6, U7, U8};
    const int j = blockIdx.x;
    const int m = blockIdx.y;
    const int h = threadIdx.x;
    UT[(size_t)m * 65536 + j * 256 + h] = Us[m][h * 256 + j];
}

// One WG: per-tree depth walk, then counting sort of all 4096 nodes by depth.
// Outputs: sched[4096] = b*128+i grouped by level; level_off[0..128]; nlevels
// stored at level_off[129].
__global__ __launch_bounds__(256) void build_schedule(
    const int* __restrict__ parents, int* __restrict__ sched,
    int* __restrict__ level_off) {
    __shared__ unsigned char depth[B_TREES][N_NODES];
    __shared__ int counts[MAXL];
    __shared__ int base[MAXL + 1];
    const int tid = threadIdx.x;
    for (int k = tid; k < MAXL; k += 256) counts[k] = 0;
    __syncthreads();
    if (tid < B_TREES) {
        depth[tid][0] = 0;
        for (int i = 1; i < N_NODES; ++i) {
            const int p = parents[tid * N_NODES + i];
            depth[tid][i] = (unsigned char)(depth[tid][p - 1] + 1);
        }
    }
    __syncthreads();
    for (int k = tid; k < B_TREES * N_NODES; k += 256)
        atomicAdd(&counts[depth[k >> 7][k & 127]], 1);
    __syncthreads();
    if (tid == 0) {
        int acc = 0;
        int nl = 0;
        for (int l = 0; l < MAXL; ++l) {
            base[l] = acc;
            acc += counts[l];
            if (counts[l] > 0) nl = l + 1;
        }
        base[MAXL] = acc;
        level_off[MAXL + 1] = nl;
    }
    __syncthreads();
    for (int k = tid; k <= MAXL; k += 256) level_off[k] = base[k];
    for (int k = tid; k < MAXL; k += 256) counts[k] = 0;
    __syncthreads();
    for (int k = tid; k < B_TREES * N_NODES; k += 256) {
        const int d = depth[k >> 7][k & 127];
        const int pos = base[d] + atomicAdd(&counts[d], 1);
        sched[pos] = k;
    }
}

// Level-parallel tree GRU. Cooperative launch: GRID_WGS x 256, grid.sync()
// between levels. Each WG processes TPB_NODES nodes of one level at a time,
// sharing every U element load across the batch.
__global__ __launch_bounds__(256, 1) void tree_scan_lp(
    const float* __restrict__ P, const float* __restrict__ UT,
    const int* __restrict__ parents,
    const int* __restrict__ sched, const int* __restrict__ level_off,
    float* __restrict__ Ssh, float* __restrict__ Sru) {
    cg::grid_group grid = cg::this_grid();
    const int h = threadIdx.x;
    const int wg = blockIdx.x;
    __shared__ float hsp_s[TPB_NODES][H_DIM];
    __shared__ float hrp_s[TPB_NODES][H_DIM];
    __shared__ float aux_s[TPB_NODES][H_DIM];   // v_sh then v2
    __shared__ float hsh_s[TPB_NODES][H_DIM];

    const float* __restrict__ U0 = UT + 0 * 65536;
    const float* __restrict__ U1 = UT + 1 * 65536;
    const float* __restrict__ U2 = UT + 2 * 65536;
    const float* __restrict__ U3 = UT + 3 * 65536;
    const float* __restrict__ U4 = UT + 4 * 65536;
    const float* __restrict__ U5 = UT + 5 * 65536;
    const float* __restrict__ U6 = UT + 6 * 65536;
    const float* __restrict__ U7 = UT + 7 * 65536;
    const float* __restrict__ U8 = UT + 8 * 65536;

    const int nlev = level_off[MAXL + 1];
    for (int l = 0; l < nlev; ++l) {
        const int lo = level_off[l], hi = level_off[l + 1];
        for (int b0 = lo + wg * TPB_NODES; b0 < hi; b0 += GRID_WGS * TPB_NODES) {
            int  node[TPB_NODES];
            bool val[TPB_NODES];
#pragma unroll
            for (int t = 0; t < TPB_NODES; ++t) {
                const int idx = b0 + t;
                val[t] = idx < hi;
                const int nd = val[t] ? sched[idx] : sched[b0];
                node[t] = nd;
                const int b = nd >> 7;
                const int p = parents[nd];
                float hs = 0.f, hr = 0.f;
                if (p != 0) {
                    const size_t pr = ((size_t)(b * N_NODES + p - 1)) * H_DIM + h;
                    hs = Ssh[pr];
                    hr = Sru[pr];
                }
                hsp_s[t][h] = hs;
                hrp_s[t][h] = hr;
            }
            __syncthreads();

            const float* Pt[TPB_NODES];
#pragma unroll
            for (int t = 0; t < TPB_NODES; ++t) Pt[t] = P + (size_t)node[t] * 1536;

            // stage 1: r_sh, z_sh
            float dr[TPB_NODES] = {0.f}, dz[TPB_NODES] = {0.f};
#pragma unroll 4
            for (int j = 0; j < H_DIM; ++j) {
                const float u0 = U0[j * 256 + h];
                const float u1 = U1[j * 256 + h];
#pragma unroll
                for (int t = 0; t < TPB_NODES; ++t) {
                    const float hv = hsp_s[t][j];
                    dr[t] = fmaf(u0, hv, dr[t]);
                    dz[t] = fmaf(u1, hv, dz[t]);
                }
            }
            float z_sh[TPB_NODES];
#pragma unroll
            for (int t = 0; t < TPB_NODES; ++t) {
                const float r_sh = sigmoidf_(Pt[t][h] + dr[t]);
                z_sh[t] = sigmoidf_(Pt[t][256 + h] + dz[t]);
                aux_s[t][h] = hsp_s[t][h] * r_sh;
            }
            __syncthreads();

            // stage 2: h_sh
            float dh[TPB_NODES] = {0.f};
#pragma unroll 4
            for (int j = 0; j < H_DIM; ++j) {
                const float u2 = U2[j * 256 + h];
#pragma unroll
                for (int t = 0; t < TPB_NODES; ++t)
                    dh[t] = fmaf(u2, aux_s[t][j], dh[t]);
            }
#pragma unroll
            for (int t = 0; t < TPB_NODES; ++t) {
                const float hsh_t = tanhf(Pt[t][512 + h] + dh[t]);
                const float h_sh = (1.f - z_sh[t]) * hsp_s[t][h] + z_sh[t] * hsh_t;
                hsh_s[t][h] = h_sh;
                if (val[t]) Ssh[(size_t)node[t] * H_DIM + h] = h_sh;
            }
            __syncthreads();

            // stage 3: r_ru, z_ru
            float er[TPB_NODES] = {0.f}, ez[TPB_NODES] = {0.f};
            float fr[TPB_NODES] = {0.f}, fz[TPB_NODES] = {0.f};
#pragma unroll 2
            for (int j = 0; j < H_DIM; ++j) {
                const float u3 = U3[j * 256 + h];
                const float u4 = U4[j * 256 + h];
                const float u6 = U6[j * 256 + h];
                const float u7 = U7[j * 256 + h];
#pragma unroll
                for (int t = 0; t < TPB_NODES; ++t) {
                    const float hrv = hrp_s[t][j];
                    const float hsv = hsh_s[t][j];
                    er[t] = fmaf(u3, hrv, er[t]);
                    ez[t] = fmaf(u4, hrv, ez[t]);
                    fr[t] = fmaf(u6, hsv, fr[t]);
                    fz[t] = fmaf(u7, hsv, fz[t]);
                }
            }
            float z_ru[TPB_NODES];
#pragma unroll
            for (int t = 0; t < TPB_NODES; ++t) {
                const float r_ru = sigmoidf_(Pt[t][768 + h] + er[t] + fr[t]);
                z_ru[t] = sigmoidf_(Pt[t][1024 + h] + ez[t] + fz[t]);
                aux_s[t][h] = hrp_s[t][h] * r_ru;
            }
            __syncthreads();

            // stage 4: h_ru
            float eh[TPB_NODES] = {0.f}, fh[TPB_NODES] = {0.f};
#pragma unroll 4
            for (int j = 0; j < H_DIM; ++j) {
                const float u5 = U5[j * 256 + h];
                const float u8 = U8[j * 256 + h];
#pragma unroll
                for (int t = 0; t < TPB_NODES; ++t) {
                    eh[t] = fmaf(u5, aux_s[t][j], eh[t]);
                    fh[t] = fmaf(u8, hsh_s[t][j], fh[t]);
                }
            }
#pragma unroll
            for (int t = 0; t < TPB_NODES; ++t) {
                const float hru_t = tanhf(Pt[t][1280 + h] + eh[t] + fh[t]);
                const float h_ru = (1.f - z_ru[t]) * hrp_s[t][h] + z_ru[t] * hru_t;
                if (val[t]) Sru[(size_t)node[t] * H_DIM + h] = h_ru;
            }
            __syncthreads();
        }
        __threadfence();
        grid.sync();
    }
}

// One WG per tree: leaf-masked max over nodes, 4 logits, softmax.
__global__ __launch_bounds__(256) void epilogue_k(
    const float* __restrict__ Sru, const int* __restrict__ is_leaf,
    const float* __restrict__ Vr, const float* __restrict__ br,
    float* __restrict__ out) {
    const int b = blockIdx.x;
    const int h = threadIdx.x;
    float m = -3.402823466e38f;
    for (int n = 0; n < N_NODES; ++n) {
        const float v = Sru[((size_t)b * N_NODES + n) * H_DIM + h];
        if (is_leaf[b * N_NODES + n] != 0) m = fmaxf(m, v);
    }
    __shared__ float hm[H_DIM];
    __shared__ float lg[4];
    hm[h] = m;
    __syncthreads();
    if (h < 4) {
        float acc = br[h];
#pragma unroll 8
        for (int j = 0; j < H_DIM; ++j) acc = fmaf(Vr[h * 256 + j], hm[j], acc);
        lg[h] = acc;
    }
    __syncthreads();
    if (h == 0) {
        const float mx = fmaxf(fmaxf(lg[0], lg[1]), fmaxf(lg[2], lg[3]));
        const float e0 = expf(lg[0] - mx);
        const float e1 = expf(lg[1] - mx);
        const float e2 = expf(lg[2] - mx);
        const float e3 = expf(lg[3] - mx);
        const float s = e0 + e1 + e2 + e3;
        out[b * 4 + 0] = e0 / s;
        out[b * 4 + 1] = e1 / s;
        out[b * 4 + 2] = e2 / s;
        out[b * 4 + 3] = e3 / s;
    }
}

extern "C" void kernel_launch(void* const* d_in, const int* in_sizes, int n_in,
                              void* d_out, int out_size, void* d_ws, size_t ws_size,
                              hipStream_t stream) {
    const float* x      = (const float*)d_in[0];
    const float* Er     = (const float*)d_in[1];
    const float* Wsr_r  = (const float*)d_in[2];
    const float* Usr_r  = (const float*)d_in[3];
    const float* Wsr_z  = (const float*)d_in[4];
    const float* Usr_z  = (const float*)d_in[5];
    const float* Wsr_h  = (const float*)d_in[6];
    const float* Usr_h  = (const float*)d_in[7];
    const float* Wr_r   = (const float*)d_in[8];
    const float* Ur_r   = (const float*)d_in[9];
    const float* Usr2r_r= (const float*)d_in[10];
    const float* Wr_z   = (const float*)d_in[11];
    const float* Ur_z   = (const float*)d_in[12];
    const float* Usr2r_z= (const float*)d_in[13];
    const float* Wr_h   = (const float*)d_in[14];
    const float* Ur_h   = (const float*)d_in[15];
    const float* Usr2r_h= (const float*)d_in[16];
    const float* Vr     = (const float*)d_in[17];
    const float* br     = (const float*)d_in[18];
    const int*   parents= (const int*)d_in[19];
    const int*   is_leaf= (const int*)d_in[20];
    float* out = (float*)d_out;

    float* ws = (float*)d_ws;
    float* xt  = ws;                         // 4096*256
    float* P   = xt + 1048576;               // 4096*1536
    float* UT  = P + 6291456;                // 9*256*256
    float* Ssh = UT + 589824;                // 32*128*256
    float* Sru = Ssh + 1048576;              // 32*128*256
    int*   sched     = (int*)(Sru + 1048576);  // 4096
    int*   level_off = sched + 4096;           // 130

    dim3 blk(256);

    gemm_nt<<<dim3(64, 4), blk, 0, stream>>>(x, Er, xt, 5000, 256);

    const float* Ws[6] = {Wsr_r, Wsr_z, Wsr_h, Wr_r, Wr_z, Wr_h};
    for (int w = 0; w < 6; ++w)
        gemm_nt<<<dim3(64, 4), blk, 0, stream>>>(xt, Ws[w], P + w * 256, 256, 1536);

    transpose_u<<<dim3(256, 9), blk, 0, stream>>>(
        Usr_r, Usr_z, Usr_h, Ur_r, Ur_z, Ur_h, Usr2r_r, Usr2r_z, Usr2r_h, UT);

    build_schedule<<<dim3(1), blk, 0, stream>>>(parents, sched, level_off);

    void* args[] = {(void*)&P, (void*)&UT, (void*)&parents,
                    (void*)&sched, (void*)&level_off,
                    (void*)&Ssh, (void*)&Sru};
    hipLaunchCooperativeKernel((const void*)tree_scan_lp,
                               dim3(GRID_WGS), blk, args, 0, stream);

    epilogue_k<<<dim3(B_TREES), blk, 0, stream>>>(Sru, is_leaf, Vr, br, out);
}

// Round 5
// 1892.423 us; speedup vs baseline: 2.5185x; 1.1328x over previous
//
#include <hip/hip_runtime.h>
#include <hip/hip_bf16.h>
#include <hip/hip_cooperative_groups.h>
#include <math.h>

namespace cg = cooperative_groups;

// ---------------------------------------------------------------------------
// B=32, N=128, D=5000, H=256, C=4
//   1) x_tilde = x @ Er^T                      (gemm_nt fp32, R2-proven)
//   2) P = x_tilde @ {6 W}^T  (6 separate gemm_nt launches, R2-proven)
//   3) UTb = bf16-packed transposed U: uint4 = 8 j-values for fixed h
//   4) build_schedule (R2-proven)
//   5) tree_scan_lp: R2 structure, U loads = 16B bf16x8 (8x fewer loads),
//      LDS state transposed to [h][t] so j-reads are single b128 broadcasts
//   6) epilogue (R2-proven)
// ---------------------------------------------------------------------------

#define H_DIM 256
#define N_NODES 128
#define B_TREES 32
#define MAXL 128
#define TPB 4
#define GRID_WGS 256

__device__ __forceinline__ float sigmoidf_(float x) {
    return 1.0f / (1.0f + expf(-x));
}
__device__ __forceinline__ unsigned bfp(float x) {  // fp32 -> bf16 bits (RNE)
    unsigned u = __float_as_uint(x);
    return (u + 0x7fffu + ((u >> 16) & 1u)) >> 16;
}
__device__ __forceinline__ float bflo(unsigned w) { return __uint_as_float(w << 16); }
__device__ __forceinline__ float bfhi(unsigned w) { return __uint_as_float(w & 0xffff0000u); }

// unpack 8 bf16 (packed in uint4) to fp32 — function, not macro (token hygiene)
__device__ __forceinline__ void unpack8(uint4 v, float* f) {
    f[0] = bflo(v.x); f[1] = bfhi(v.x);
    f[2] = bflo(v.y); f[3] = bfhi(v.y);
    f[4] = bflo(v.z); f[5] = bfhi(v.z);
    f[6] = bflo(v.w); f[7] = bfhi(v.w);
}

// C[M,N] = A[M,K] @ B[N,K]^T   (row-major, K contiguous; M,N mult of 64)
__global__ __launch_bounds__(256) void gemm_nt(
    const float* __restrict__ A, const float* __restrict__ B,
    float* __restrict__ C, int K, int ldc) {
    __shared__ float As[64][68];
    __shared__ float Bs[64][68];
    const int tid = threadIdx.x;
    const int bm = blockIdx.x, bn = blockIdx.y;
    const int tx = tid & 15, ty = tid >> 4;
    float acc[4][4] = {{0.f}};
    const int nk = (K + 63) >> 6;
    for (int kt = 0; kt < nk; ++kt) {
        const int k0 = kt << 6;
#pragma unroll
        for (int it = 0; it < 4; ++it) {
            const int f = tid + it * 256;
            const int row = f >> 4;
            const int cq = f & 15;
            const int kcol = k0 + cq * 4;
            float4 av = make_float4(0.f, 0.f, 0.f, 0.f);
            float4 bv = make_float4(0.f, 0.f, 0.f, 0.f);
            if (kcol < K) {
                av = *(const float4*)(A + (size_t)(bm * 64 + row) * K + kcol);
                bv = *(const float4*)(B + (size_t)(bn * 64 + row) * K + kcol);
            }
            *(float4*)&As[row][cq * 4] = av;
            *(float4*)&Bs[row][cq * 4] = bv;
        }
        __syncthreads();
#pragma unroll 4
        for (int kk = 0; kk < 64; kk += 4) {
            float4 a[4], bq[4];
#pragma unroll
            for (int i = 0; i < 4; ++i) a[i] = *(const float4*)&As[ty * 4 + i][kk];
#pragma unroll
            for (int j = 0; j < 4; ++j) bq[j] = *(const float4*)&Bs[tx * 4 + j][kk];
#pragma unroll
            for (int i = 0; i < 4; ++i)
#pragma unroll
                for (int j = 0; j < 4; ++j)
                    acc[i][j] += a[i].x * bq[j].x + a[i].y * bq[j].y +
                                 a[i].z * bq[j].z + a[i].w * bq[j].w;
        }
        __syncthreads();
    }
#pragma unroll
    for (int i = 0; i < 4; ++i) {
        float4 o = make_float4(acc[i][0], acc[i][1], acc[i][2], acc[i][3]);
        *(float4*)(C + (size_t)(bm * 64 + ty * 4 + i) * ldc + bn * 64 + tx * 4) = o;
    }
}

// UTb[(m*32 + jblk)*256 + h] = uint4 of 8 bf16 = U_m[h][8*jblk .. 8*jblk+7]
__global__ __launch_bounds__(256) void transpose_pack_u(
    const float* __restrict__ U0, const float* __restrict__ U1,
    const float* __restrict__ U2, const float* __restrict__ U3,
    const float* __restrict__ U4, const float* __restrict__ U5,
    const float* __restrict__ U6, const float* __restrict__ U7,
    const float* __restrict__ U8, uint4* __restrict__ UTb) {
    const float* Us[9] = {U0, U1, U2, U3, U4, U5, U6, U7, U8};
    const int jb = blockIdx.x;     // 0..31
    const int m = blockIdx.y;      // 0..8
    const int h = threadIdx.x;     // 0..255
    const float* U = Us[m] + (size_t)h * 256 + jb * 8;
    uint4 v;
    v.x = bfp(U[0]) | (bfp(U[1]) << 16);
    v.y = bfp(U[2]) | (bfp(U[3]) << 16);
    v.z = bfp(U[4]) | (bfp(U[5]) << 16);
    v.w = bfp(U[6]) | (bfp(U[7]) << 16);
    UTb[(size_t)(m * 32 + jb) * 256 + h] = v;
}

__global__ __launch_bounds__(256) void build_schedule(
    const int* __restrict__ parents, int* __restrict__ sched,
    int* __restrict__ level_off) {
    __shared__ unsigned char depth[B_TREES][N_NODES];
    __shared__ int counts[MAXL];
    __shared__ int base[MAXL + 1];
    const int tid = threadIdx.x;
    for (int k = tid; k < MAXL; k += 256) counts[k] = 0;
    __syncthreads();
    if (tid < B_TREES) {
        depth[tid][0] = 0;
        for (int i = 1; i < N_NODES; ++i) {
            const int p = parents[tid * N_NODES + i];
            depth[tid][i] = (unsigned char)(depth[tid][p - 1] + 1);
        }
    }
    __syncthreads();
    for (int k = tid; k < B_TREES * N_NODES; k += 256)
        atomicAdd(&counts[depth[k >> 7][k & 127]], 1);
    __syncthreads();
    if (tid == 0) {
        int acc = 0;
        int nl = 0;
        for (int l = 0; l < MAXL; ++l) {
            base[l] = acc;
            acc += counts[l];
            if (counts[l] > 0) nl = l + 1;
        }
        base[MAXL] = acc;
        level_off[MAXL + 1] = nl;
    }
    __syncthreads();
    for (int k = tid; k <= MAXL; k += 256) level_off[k] = base[k];
    for (int k = tid; k < MAXL; k += 256) counts[k] = 0;
    __syncthreads();
    for (int k = tid; k < B_TREES * N_NODES; k += 256) {
        const int d = depth[k >> 7][k & 127];
        const int pos = base[d] + atomicAdd(&counts[d], 1);
        sched[pos] = k;
    }
}

// Level-parallel tree GRU. R2 control flow; bf16x8 U loads; LDS state [h][t].
__global__ __launch_bounds__(256, 1) void tree_scan_lp(
    const float* __restrict__ P, const uint4* __restrict__ UTb,
    const int* __restrict__ parents,
    const int* __restrict__ sched, const int* __restrict__ level_off,
    float* __restrict__ Ssh, float* __restrict__ Sru) {
    cg::grid_group grid = cg::this_grid();
    const int h = threadIdx.x;
    const int wg = blockIdx.x;
    __shared__ float hsp_s[H_DIM][TPB];
    __shared__ float hrp_s[H_DIM][TPB];
    __shared__ float aux_s[H_DIM][TPB];
    __shared__ float hsh_s[H_DIM][TPB];

    const uint4* __restrict__ U0b = UTb + 0 * 8192;
    const uint4* __restrict__ U1b = UTb + 1 * 8192;
    const uint4* __restrict__ U2b = UTb + 2 * 8192;
    const uint4* __restrict__ U3b = UTb + 3 * 8192;
    const uint4* __restrict__ U4b = UTb + 4 * 8192;
    const uint4* __restrict__ U5b = UTb + 5 * 8192;
    const uint4* __restrict__ U6b = UTb + 6 * 8192;
    const uint4* __restrict__ U7b = UTb + 7 * 8192;
    const uint4* __restrict__ U8b = UTb + 8 * 8192;

    const int nlev = level_off[MAXL + 1];
    for (int l = 0; l < nlev; ++l) {
        const int lo = level_off[l], hi = level_off[l + 1];
        for (int b0 = lo + wg * TPB; b0 < hi; b0 += GRID_WGS * TPB) {
            int  node[TPB];
            bool val[TPB];
            float phs[TPB], phr[TPB];
#pragma unroll
            for (int t = 0; t < TPB; ++t) {
                const int idx = b0 + t;
                val[t] = idx < hi;
                const int nd = val[t] ? sched[idx] : sched[b0];
                node[t] = nd;
                const int p = parents[nd];
                float hs = 0.f, hr = 0.f;
                if (p != 0) {
                    const size_t pr = ((size_t)((nd & ~127) + p - 1)) * H_DIM + h;
                    hs = Ssh[pr];
                    hr = Sru[pr];
                }
                phs[t] = hs;
                phr[t] = hr;
            }
            *(float4*)&hsp_s[h][0] = make_float4(phs[0], phs[1], phs[2], phs[3]);
            *(float4*)&hrp_s[h][0] = make_float4(phr[0], phr[1], phr[2], phr[3]);
            __syncthreads();

            // ---------------- stage 1: r_sh, z_sh ----------------
            float pr_[TPB], pz_[TPB];
#pragma unroll
            for (int t = 0; t < TPB; ++t) {
                const float* Pi = P + (size_t)node[t] * 1536;
                pr_[t] = Pi[h];
                pz_[t] = Pi[256 + h];
            }
            float dr[TPB] = {0.f, 0.f, 0.f, 0.f};
            float dz[TPB] = {0.f, 0.f, 0.f, 0.f};
#pragma unroll 4
            for (int jb = 0; jb < 32; ++jb) {
                const uint4 w0 = U0b[jb * 256 + h];
                const uint4 w1 = U1b[jb * 256 + h];
                float a[8], c[8];
                unpack8(w0, a);
                unpack8(w1, c);
#pragma unroll
                for (int q = 0; q < 8; ++q) {
                    const float4 hv = *(const float4*)&hsp_s[jb * 8 + q][0];
                    const float hv4[4] = {hv.x, hv.y, hv.z, hv.w};
#pragma unroll
                    for (int t = 0; t < TPB; ++t) {
                        dr[t] = fmaf(a[q], hv4[t], dr[t]);
                        dz[t] = fmaf(c[q], hv4[t], dz[t]);
                    }
                }
            }
            float z_sh[TPB], vsh[TPB];
#pragma unroll
            for (int t = 0; t < TPB; ++t) {
                const float r_sh = sigmoidf_(pr_[t] + dr[t]);
                z_sh[t] = sigmoidf_(pz_[t] + dz[t]);
                vsh[t] = phs[t] * r_sh;
            }
            *(float4*)&aux_s[h][0] = make_float4(vsh[0], vsh[1], vsh[2], vsh[3]);
            __syncthreads();

            // ---------------- stage 2: h_sh ----------------
            float ph_[TPB];
#pragma unroll
            for (int t = 0; t < TPB; ++t)
                ph_[t] = P[(size_t)node[t] * 1536 + 512 + h];
            float dh[TPB] = {0.f, 0.f, 0.f, 0.f};
#pragma unroll 8
            for (int jb = 0; jb < 32; ++jb) {
                const uint4 w2 = U2b[jb * 256 + h];
                float a[8];
                unpack8(w2, a);
#pragma unroll
                for (int q = 0; q < 8; ++q) {
                    const float4 hv = *(const float4*)&aux_s[jb * 8 + q][0];
                    const float hv4[4] = {hv.x, hv.y, hv.z, hv.w};
#pragma unroll
                    for (int t = 0; t < TPB; ++t)
                        dh[t] = fmaf(a[q], hv4[t], dh[t]);
                }
            }
            float hsh[TPB];
#pragma unroll
            for (int t = 0; t < TPB; ++t) {
                const float hsh_t = tanhf(ph_[t] + dh[t]);
                hsh[t] = (1.f - z_sh[t]) * phs[t] + z_sh[t] * hsh_t;
                if (val[t]) Ssh[(size_t)node[t] * H_DIM + h] = hsh[t];
            }
            *(float4*)&hsh_s[h][0] = make_float4(hsh[0], hsh[1], hsh[2], hsh[3]);
            __syncthreads();

            // ---------------- stage 3: r_ru, z_ru ----------------
            float pru_[TPB], pzu_[TPB];
#pragma unroll
            for (int t = 0; t < TPB; ++t) {
                const float* Pi = P + (size_t)node[t] * 1536;
                pru_[t] = Pi[768 + h];
                pzu_[t] = Pi[1024 + h];
            }
            float er[TPB] = {0.f, 0.f, 0.f, 0.f};
            float ez[TPB] = {0.f, 0.f, 0.f, 0.f};
            float fr[TPB] = {0.f, 0.f, 0.f, 0.f};
            float fz[TPB] = {0.f, 0.f, 0.f, 0.f};
#pragma unroll 2
            for (int jb = 0; jb < 32; ++jb) {
                const uint4 w3 = U3b[jb * 256 + h];
                const uint4 w4 = U4b[jb * 256 + h];
                const uint4 w6 = U6b[jb * 256 + h];
                const uint4 w7 = U7b[jb * 256 + h];
                float a3[8], a4[8], a6[8], a7[8];
                unpack8(w3, a3);
                unpack8(w4, a4);
                unpack8(w6, a6);
                unpack8(w7, a7);
#pragma unroll
                for (int q = 0; q < 8; ++q) {
                    const float4 hr4 = *(const float4*)&hrp_s[jb * 8 + q][0];
                    const float4 hs4 = *(const float4*)&hsh_s[jb * 8 + q][0];
                    const float hrv[4] = {hr4.x, hr4.y, hr4.z, hr4.w};
                    const float hsv[4] = {hs4.x, hs4.y, hs4.z, hs4.w};
#pragma unroll
                    for (int t = 0; t < TPB; ++t) {
                        er[t] = fmaf(a3[q], hrv[t], er[t]);
                        ez[t] = fmaf(a4[q], hrv[t], ez[t]);
                        fr[t] = fmaf(a6[q], hsv[t], fr[t]);
                        fz[t] = fmaf(a7[q], hsv[t], fz[t]);
                    }
                }
            }
            float z_ru[TPB], v2[TPB];
#pragma unroll
            for (int t = 0; t < TPB; ++t) {
                const float r_ru = sigmoidf_(pru_[t] + er[t] + fr[t]);
                z_ru[t] = sigmoidf_(pzu_[t] + ez[t] + fz[t]);
                v2[t] = phr[t] * r_ru;
            }
            *(float4*)&aux_s[h][0] = make_float4(v2[0], v2[1], v2[2], v2[3]);
            __syncthreads();

            // ---------------- stage 4: h_ru ----------------
            float phu_[TPB];
#pragma unroll
            for (int t = 0; t < TPB; ++t)
                phu_[t] = P[(size_t)node[t] * 1536 + 1280 + h];
            float eh[TPB] = {0.f, 0.f, 0.f, 0.f};
            float fh[TPB] = {0.f, 0.f, 0.f, 0.f};
#pragma unroll 4
            for (int jb = 0; jb < 32; ++jb) {
                const uint4 w5 = U5b[jb * 256 + h];
                const uint4 w8 = U8b[jb * 256 + h];
                float a5[8], a8[8];
                unpack8(w5, a5);
                unpack8(w8, a8);
#pragma unroll
                for (int q = 0; q < 8; ++q) {
                    const float4 v4 = *(const float4*)&aux_s[jb * 8 + q][0];
                    const float4 s4 = *(const float4*)&hsh_s[jb * 8 + q][0];
                    const float vv[4] = {v4.x, v4.y, v4.z, v4.w};
                    const float sv[4] = {s4.x, s4.y, s4.z, s4.w};
#pragma unroll
                    for (int t = 0; t < TPB; ++t) {
                        eh[t] = fmaf(a5[q], vv[t], eh[t]);
                        fh[t] = fmaf(a8[q], sv[t], fh[t]);
                    }
                }
            }
#pragma unroll
            for (int t = 0; t < TPB; ++t) {
                const float hru_t = tanhf(phu_[t] + eh[t] + fh[t]);
                const float h_ru = (1.f - z_ru[t]) * phr[t] + z_ru[t] * hru_t;
                if (val[t]) Sru[(size_t)node[t] * H_DIM + h] = h_ru;
            }
            __syncthreads();
        }
        __threadfence();
        grid.sync();
    }
}

__global__ __launch_bounds__(256) void epilogue_k(
    const float* __restrict__ Sru, const int* __restrict__ is_leaf,
    const float* __restrict__ Vr, const float* __restrict__ br,
    float* __restrict__ out) {
    const int b = blockIdx.x;
    const int h = threadIdx.x;
    float m = -3.402823466e38f;
    for (int n = 0; n < N_NODES; ++n) {
        const float v = Sru[((size_t)b * N_NODES + n) * H_DIM + h];
        if (is_leaf[b * N_NODES + n] != 0) m = fmaxf(m, v);
    }
    __shared__ float hm[H_DIM];
    __shared__ float lg[4];
    hm[h] = m;
    __syncthreads();
    if (h < 4) {
        float acc = br[h];
#pragma unroll 8
        for (int j = 0; j < H_DIM; ++j) acc = fmaf(Vr[h * 256 + j], hm[j], acc);
        lg[h] = acc;
    }
    __syncthreads();
    if (h == 0) {
        const float mx = fmaxf(fmaxf(lg[0], lg[1]), fmaxf(lg[2], lg[3]));
        const float e0 = expf(lg[0] - mx);
        const float e1 = expf(lg[1] - mx);
        const float e2 = expf(lg[2] - mx);
        const float e3 = expf(lg[3] - mx);
        const float s = e0 + e1 + e2 + e3;
        out[b * 4 + 0] = e0 / s;
        out[b * 4 + 1] = e1 / s;
        out[b * 4 + 2] = e2 / s;
        out[b * 4 + 3] = e3 / s;
    }
}

extern "C" void kernel_launch(void* const* d_in, const int* in_sizes, int n_in,
                              void* d_out, int out_size, void* d_ws, size_t ws_size,
                              hipStream_t stream) {
    const float* x      = (const float*)d_in[0];
    const float* Er     = (const float*)d_in[1];
    const float* Wsr_r  = (const float*)d_in[2];
    const float* Usr_r  = (const float*)d_in[3];
    const float* Wsr_z  = (const float*)d_in[4];
    const float* Usr_z  = (const float*)d_in[5];
    const float* Wsr_h  = (const float*)d_in[6];
    const float* Usr_h  = (const float*)d_in[7];
    const float* Wr_r   = (const float*)d_in[8];
    const float* Ur_r   = (const float*)d_in[9];
    const float* Usr2r_r= (const float*)d_in[10];
    const float* Wr_z   = (const float*)d_in[11];
    const float* Ur_z   = (const float*)d_in[12];
    const float* Usr2r_z= (const float*)d_in[13];
    const float* Wr_h   = (const float*)d_in[14];
    const float* Ur_h   = (const float*)d_in[15];
    const float* Usr2r_h= (const float*)d_in[16];
    const float* Vr     = (const float*)d_in[17];
    const float* br     = (const float*)d_in[18];
    const int*   parents= (const int*)d_in[19];
    const int*   is_leaf= (const int*)d_in[20];
    float* out = (float*)d_out;

    float* ws = (float*)d_ws;
    float* xt  = ws;                           // 4096*256
    float* P   = xt + 1048576;                 // 4096*1536
    uint4* UTb = (uint4*)(P + 6291456);        // 9*32*256 uint4 (16B aligned)
    float* Ssh = (float*)(UTb + 73728);        // 32*128*256
    float* Sru = Ssh + 1048576;                // 32*128*256
    int*   sched     = (int*)(Sru + 1048576);
    int*   level_off = sched + 4096;

    dim3 blk(256);

    gemm_nt<<<dim3(64, 4), blk, 0, stream>>>(x, Er, xt, 5000, 256);

    const float* Ws[6] = {Wsr_r, Wsr_z, Wsr_h, Wr_r, Wr_z, Wr_h};
    for (int w = 0; w < 6; ++w)
        gemm_nt<<<dim3(64, 4), blk, 0, stream>>>(xt, Ws[w], P + w * 256, 256, 1536);

    transpose_pack_u<<<dim3(32, 9), blk, 0, stream>>>(
        Usr_r, Usr_z, Usr_h, Ur_r, Ur_z, Ur_h, Usr2r_r, Usr2r_z, Usr2r_h, UTb);

    build_schedule<<<dim3(1), blk, 0, stream>>>(parents, sched, level_off);

    void* args[] = {(void*)&P, (void*)&UTb, (void*)&parents,
                    (void*)&sched, (void*)&level_off,
                    (void*)&Ssh, (void*)&Sru};
    (void)hipLaunchCooperativeKernel((const void*)tree_scan_lp,
                                     dim3(GRID_WGS), blk, args, 0, stream);

    epilogue_k<<<dim3(B_TREES), blk, 0, stream>>>(Sru, is_leaf, Vr, br, out);
}